// Round 11
// baseline (199.486 us; speedup 1.0000x reference)
//
#include <hip/hip_runtime.h>
#include <hip/hip_bf16.h>

// MultiHeadSelfAttention  B=2, S=4096, D=512, H=8, dk=64
// R11: attn = R7 low-register body (M=32/wave, dbuf K/V, 1 barrier/tile,
//      S^T=K*Q^T in-register P packing) x key-split grid (32,8,4)=1024 blocks.
//      gfx950 unified VGPR/AGPR file: R8/R10 body needs ~164 regs -> HW caps
//      2 waves/SIMD regardless of grid (why R10 was neutral). R7 body = 88+32
//      = 120 <= 128 -> 4 blocks/CU possible; key-split grid supplies them.
//      combine fused into gemm_out (A-staging sums 2 f32 chunks, /l, ->bf16).
// kappa(m) = 32*(m>>5) + 8*((m>>2)&3) + 4*((m>>4)&1) + (m&3)  per 64-group,
// baked into V^T global layout so P packs in-register into PV A-frags.

#define DMODEL 512
#define SEQ    4096
#define NTOK   8192
#define LDQK   1024

using f32x4 = __attribute__((ext_vector_type(4))) float;
using s16x8 = __attribute__((ext_vector_type(8))) short;
using u16x8 = __attribute__((ext_vector_type(8))) unsigned short;

static __device__ __forceinline__ unsigned short f2bf(float f) {
  union { float f; unsigned u; } v; v.f = f;
  unsigned r = v.u + 0x7fff + ((v.u >> 16) & 1);   // RNE
  return (unsigned short)(r >> 16);
}

static __device__ __forceinline__ unsigned pack_bf2(float lo, float hi) {
  __hip_bfloat162 t = __float22bfloat162_rn(make_float2(lo, hi));
  union { __hip_bfloat162 b; unsigned u; } c; c.b = t; return c.u;
}

// async global->LDS, 16B per lane; lds base wave-uniform, lane i -> base+16i.
static __device__ __forceinline__ void gll16(const void* g, void* l) {
  __builtin_amdgcn_global_load_lds(
      (const __attribute__((address_space(1))) unsigned int*)g,
      (__attribute__((address_space(3))) unsigned int*)l, 16, 0, 0);
}

// Fused prep: blocks 0..1023 cast x -> bf16; blocks 1024..1279 transpose one
// 64x64 tile of one W into Wall = [Wq'|Wk|Wv|Wo] (N-major), Wq scaled by c2.
__global__ void prep_kernel(const float* __restrict__ x,
                            const float* __restrict__ Wq,
                            const float* __restrict__ Wk,
                            const float* __restrict__ Wv,
                            const float* __restrict__ Wo,
                            unsigned short* __restrict__ xb,
                            unsigned short* __restrict__ Wall, float c2) {
  __shared__ float T[64][65];
  const int bx = blockIdx.x;
  if (bx < 1024) {
    for (int i = bx * 256 + threadIdx.x; i < NTOK * DMODEL / 4; i += 262144) {
      float4 v = ((const float4*)x)[i];
      ushort4 o;
      o.x = f2bf(v.x); o.y = f2bf(v.y); o.z = f2bf(v.z); o.w = f2bf(v.w);
      ((ushort4*)xb)[i] = o;
    }
    return;
  }
  const int t = bx - 1024;
  const int y = t >> 6, sub = t & 63;
  const float* W = (y == 0) ? Wq : (y == 1) ? Wk : (y == 2) ? Wv : Wo;
  const float scale = (y == 0) ? c2 : 1.0f;
  const int tk = (sub & 7) * 64;
  const int tn = (sub >> 3) * 64;
  const int r  = threadIdx.x >> 2;
  const int cq = threadIdx.x & 3;
#pragma unroll
  for (int i = 0; i < 4; ++i) {
    int c = (cq + 4 * i) * 4;
    float4 v = *(const float4*)&W[(size_t)(tk + r) * 512 + tn + c];
    T[r][c + 0] = v.x * scale; T[r][c + 1] = v.y * scale;
    T[r][c + 2] = v.z * scale; T[r][c + 3] = v.w * scale;
  }
  __syncthreads();
  const int n  = threadIdx.x >> 2;
  const int k0 = (threadIdx.x & 3) * 16;
#pragma unroll
  for (int j4 = 0; j4 < 4; ++j4) {
    ushort4 o;
    o.x = f2bf(T[k0 + j4 * 4 + 0][n]);
    o.y = f2bf(T[k0 + j4 * 4 + 1][n]);
    o.z = f2bf(T[k0 + j4 * 4 + 2][n]);
    o.w = f2bf(T[k0 + j4 * 4 + 3][n]);
    *(ushort4*)&Wall[(size_t)y * 262144 + (size_t)(tn + n) * 512 + tk + k0 + j4 * 4] = o;
  }
}

// Fused QK + V^T GEMM. grid (64, 12). global_load_lds staging (m97 2-barrier).
//  by 0..7 : QK block  — C[8192 x 1024] = xb @ [Wq'|Wk]^T, bf16 row-major.
//  by 8..11: V^T block — C[512 x 8192] = Wv_t @ xb^T, stored batched
//            [b][m=h*64+dk][s] with kappa-permuted s within 64-groups.
__global__ __launch_bounds__(256, 3) void gemm_qkv(
    const unsigned short* __restrict__ xb,
    const unsigned short* __restrict__ Wall,
    unsigned short* __restrict__ QKb,
    unsigned short* __restrict__ Vtb)
{
  __shared__ unsigned short As[128 * 32];
  __shared__ unsigned short Bs[128 * 32];
  const int by = blockIdx.y;
  const bool vmode = (by >= 8);
  const unsigned short* A  = vmode ? (Wall + 2 * 262144) : xb;
  const unsigned short* Bt = vmode ? xb : Wall;
  const size_t bm = vmode ? (size_t)(by - 8) * 128 : (size_t)blockIdx.x * 128;
  const size_t bn = vmode ? (size_t)blockIdx.x * 128 : (size_t)by * 128;
  const int tid  = threadIdx.x;
  const int wave = tid >> 6, lane = tid & 63;
  const int q4 = lane >> 4, ln = lane & 15;
  const int wm = (wave >> 1) * 64, wn = (wave & 1) * 64;
  f32x4 acc[4][4] = {};
  const int srow = wave * 16 + (lane >> 2);
  const int scol = (lane & 3) * 8;

  const unsigned short* Ag  = A  + (bm + srow)      * 512 + scol;
  const unsigned short* Ag2 = A  + (bm + 64 + srow) * 512 + scol;
  const unsigned short* Bg  = Bt + (bn + srow)      * 512 + scol;
  const unsigned short* Bg2 = Bt + (bn + 64 + srow) * 512 + scol;
  unsigned short* Ad  = As + wave * 512;
  unsigned short* Ad2 = As + 2048 + wave * 512;
  unsigned short* Bd  = Bs + wave * 512;
  unsigned short* Bd2 = Bs + 2048 + wave * 512;

  for (int kt = 0; kt < 512; kt += 32) {
    __syncthreads();
    gll16(Ag + kt,  Ad);
    gll16(Ag2 + kt, Ad2);
    gll16(Bg + kt,  Bd);
    gll16(Bg2 + kt, Bd2);
    __syncthreads();
    s16x8 af[4], bfr[4];
#pragma unroll
    for (int i = 0; i < 4; i++)
      af[i] = *(const s16x8*)(As + (wm + i * 16 + ln) * 32 + q4 * 8);
#pragma unroll
    for (int i = 0; i < 4; i++)
      bfr[i] = *(const s16x8*)(Bs + (wn + i * 16 + ln) * 32 + q4 * 8);
#pragma unroll
    for (int mi = 0; mi < 4; mi++)
#pragma unroll
      for (int ni = 0; ni < 4; ni++)
        acc[mi][ni] = __builtin_amdgcn_mfma_f32_16x16x32_bf16(
            af[mi], bfr[ni], acc[mi][ni], 0, 0, 0);
  }
#pragma unroll
  for (int mi = 0; mi < 4; mi++)
#pragma unroll
    for (int r = 0; r < 4; ++r) {
      size_t row = bm + wm + mi * 16 + q4 * 4 + r;
#pragma unroll
      for (int ni = 0; ni < 4; ni++) {
        size_t col = bn + wn + ni * 16 + ln;
        unsigned short hv = f2bf(acc[mi][ni][r]);
        if (!vmode) {
          QKb[row * 1024 + col] = hv;
        } else {
          int b = (int)(col >> 12), s = (int)(col & 4095);
          // kappa(s%64): slot holding key s for PV A-frag alignment
          int sp = (s & ~63) | (s & 32) | (((s >> 2) & 3) << 3) |
                   (((s >> 4) & 1) << 2) | (s & 3);
          Vtb[(size_t)b * 2097152 + row * 4096 + sp] = hv;
        }
      }
    }
}

// Flash-lite attention, key-split, low-register body.
// grid (32 qt, 8 h, 4 z=b*2+ck) = 1024 blocks; 4 waves x 32 q-rows = 128
// q-rows/block; each block covers keys [ck*2048, ck*2048+2048) in 32 tiles.
// S^T = K*Q^T; P packed in-register into PV A-frags (kappa slots). Dbuf K/V,
// ONE barrier/tile. Writes f32 O/l chunk-partials (normalize in gemm_out).
// launch_bounds(256,2): do NOT raise (R9: (256,4) forced spills, ~2GB traffic).
__global__ __launch_bounds__(256, 2) void attn_kernel(
    const unsigned short* __restrict__ QK,   // NTOK x 1024 [Q'|K]
    const unsigned short* __restrict__ Vt,   // [b*8+h][64 dk][4096 s-kappa]
    float* __restrict__ Opart,               // [ck][8192][512] f32
    float* __restrict__ Lpart)               // [ck][b*8+h][4096] f32
{
  const int qt = blockIdx.x, h = blockIdx.y, z = blockIdx.z;
  const int b = z >> 1, ck = z & 1;
  const int tid = threadIdx.x, wave = tid >> 6, lane = tid & 63;
  const int q4 = lane >> 4, ln = lane & 15;
  __shared__ unsigned short Ks[2][64 * 72];   // [buf][key][dk]
  __shared__ unsigned short Vs[2][64 * 72];   // [buf][dk][key-kappa]
  const size_t rowbase = (size_t)b * SEQ;
  const size_t qrow0   = (size_t)qt * 128 + wave * 32;
  const unsigned short* Kp  = QK + rowbase * LDQK + 512 + h * 64;
  const unsigned short* VTp = Vt + ((size_t)(b * 8 + h) * 64) * SEQ;

  s16x8 qf[2][2];   // B-frags: B[n=ln (q)][k=q4*8+j]
#pragma unroll
  for (int mf = 0; mf < 2; ++mf) {
    const unsigned short* q = QK + (rowbase + qrow0 + mf * 16 + ln) * LDQK + h * 64;
    qf[mf][0] = *(const s16x8*)(q + q4 * 8);
    qf[mf][1] = *(const s16x8*)(q + 32 + q4 * 8);
  }
  f32x4 o[2][4] = {};
  float lp[2] = {};                     // per-lane l partials (q = ln)

  const int srow = tid >> 2;            // 0..63
  const int scol = (tid & 3) * 16;      // 0,16,32,48

  const unsigned short* kgp = Kp  + (size_t)(ck * 2048 + srow) * LDQK + scol;
  const unsigned short* vgp = VTp + (size_t)srow * SEQ + ck * 2048 + scol;

  // tile 0 -> regs -> buf0; prefetch tile 1 -> regs
  u16x8 kr  = *(const u16x8*)kgp;
  u16x8 kr2 = *(const u16x8*)(kgp + 8);
  u16x8 vr  = *(const u16x8*)vgp;
  u16x8 vr2 = *(const u16x8*)(vgp + 8);
  *(u16x8*)(Ks[0] + srow * 72 + scol)     = kr;
  *(u16x8*)(Ks[0] + srow * 72 + scol + 8) = kr2;
  *(u16x8*)(Vs[0] + srow * 72 + scol)     = vr;
  *(u16x8*)(Vs[0] + srow * 72 + scol + 8) = vr2;
  kgp += (size_t)64 * LDQK;  vgp += 64;
  kr  = *(const u16x8*)kgp;
  kr2 = *(const u16x8*)(kgp + 8);
  vr  = *(const u16x8*)vgp;
  vr2 = *(const u16x8*)(vgp + 8);
  __syncthreads();

  for (int t = 0; t < 32; ++t) {
    const int cur = t & 1;
    const unsigned short* Kc = Ks[cur];
    const unsigned short* Vc = Vs[cur];

    // S^T = K Q'^T : A=K frags (m=key), B=Q frags (n=q). K shared across mf.
    f32x4 s4[2][4] = {};
#pragma unroll
    for (int ni = 0; ni < 4; ni++) {
      const unsigned short* kb = Kc + (ni * 16 + ln) * 72 + q4 * 8;
      s16x8 kf0 = *(const s16x8*)kb;
      s16x8 kf1 = *(const s16x8*)(kb + 32);
#pragma unroll
      for (int mf = 0; mf < 2; ++mf) {
        s4[mf][ni] = __builtin_amdgcn_mfma_f32_16x16x32_bf16(kf0, qf[mf][0], s4[mf][ni], 0, 0, 0);
        s4[mf][ni] = __builtin_amdgcn_mfma_f32_16x16x32_bf16(kf1, qf[mf][1], s4[mf][ni], 0, 0, 0);
      }
    }
    // hoist V frags (independent of exp2 chain)
    s16x8 vf[2][4];
#pragma unroll
    for (int ks = 0; ks < 2; ++ks)
#pragma unroll
      for (int ni = 0; ni < 4; ni++)
        vf[ks][ni] = *(const s16x8*)(Vc + (ni * 16 + ln) * 72 + ks * 32 + q4 * 8);

    // p = exp2(s^T): all 16 values belong to q=ln. Pack straight into PV
    // A-frags: elem j of pf[ks] = e[ni=2ks+(j>>2)][r=j&3]  (kappa-aligned).
    s16x8 pf[2][2];
#pragma unroll
    for (int mf = 0; mf < 2; ++mf) {
      float e[4][4];
      float ls = 0.f;
#pragma unroll
      for (int ni = 0; ni < 4; ni++)
#pragma unroll
        for (int r = 0; r < 4; ++r) {
          e[ni][r] = __builtin_amdgcn_exp2f(s4[mf][ni][r]);
          ls += e[ni][r];
        }
      lp[mf] += ls;
#pragma unroll
      for (int ks = 0; ks < 2; ++ks) {
        union { s16x8 v; unsigned u[4]; } pu;
        pu.u[0] = pack_bf2(e[2 * ks][0],     e[2 * ks][1]);
        pu.u[1] = pack_bf2(e[2 * ks][2],     e[2 * ks][3]);
        pu.u[2] = pack_bf2(e[2 * ks + 1][0], e[2 * ks + 1][1]);
        pu.u[3] = pack_bf2(e[2 * ks + 1][2], e[2 * ks + 1][3]);
        pf[mf][ks] = pu.v;
      }
    }
    // O += P V
#pragma unroll
    for (int ks = 0; ks < 2; ++ks)
#pragma unroll
      for (int ni = 0; ni < 4; ni++)
#pragma unroll
        for (int mf = 0; mf < 2; ++mf)
          o[mf][ni] = __builtin_amdgcn_mfma_f32_16x16x32_bf16(pf[mf][ks], vf[ks][ni], o[mf][ni], 0, 0, 0);

    // stage tile t+1 into other buffer; prefetch tile t+2
    if (t + 1 < 32) {
      unsigned short* Kn = Ks[cur ^ 1];
      unsigned short* Vn = Vs[cur ^ 1];
      *(u16x8*)(Kn + srow * 72 + scol)     = kr;
      *(u16x8*)(Kn + srow * 72 + scol + 8) = kr2;
      *(u16x8*)(Vn + srow * 72 + scol)     = vr;
      *(u16x8*)(Vn + srow * 72 + scol + 8) = vr2;
      if (t + 2 < 32) {
        kgp += (size_t)64 * LDQK;  vgp += 64;
        kr  = *(const u16x8*)kgp;
        kr2 = *(const u16x8*)(kgp + 8);
        vr  = *(const u16x8*)vgp;
        vr2 = *(const u16x8*)(vgp + 8);
      }
    }
    __syncthreads();   // single barrier per tile
  }
  // l: sum the 4 q4-replicas; lane (q4==0, ln) holds l for q = ln
#pragma unroll
  for (int mf = 0; mf < 2; ++mf) {
    float l = lp[mf];
    l += __shfl_xor(l, 16, 64);
    l += __shfl_xor(l, 32, 64);
    if (q4 == 0)
      Lpart[(size_t)ck * 65536 + (size_t)(b * 8 + h) * 4096 + qrow0 + mf * 16 + ln] = l;
  }
  // O chunk-partials (f32, un-normalized)
  float* Opc = Opart + (size_t)ck * NTOK * DMODEL;
#pragma unroll
  for (int mf = 0; mf < 2; ++mf)
#pragma unroll
    for (int r = 0; r < 4; ++r) {
      size_t row = rowbase + qrow0 + mf * 16 + q4 * 4 + r;
#pragma unroll
      for (int ni = 0; ni < 4; ni++)
        Opc[row * DMODEL + h * 64 + ni * 16 + ln] = o[mf][ni][r];
    }
}

// out = ((Op0+Op1)/l) @ Wo^T : M=8192 N=512 K=512, tile 128x64, grid (64,8).
// A-staging fuses the combine: read both f32 chunks, sum, *1/l, pack bf16.
__global__ __launch_bounds__(256, 2) void gemm_out(
    const float* __restrict__ Opart,
    const float* __restrict__ Lpart,
    const unsigned short* __restrict__ Bt,
    float* __restrict__ C)
{
  __shared__ unsigned short As[128 * 32];
  __shared__ unsigned short Bs[64 * 32];
  const int tid  = threadIdx.x;
  const int wave = tid >> 6, lane = tid & 63;
  const int q4 = lane >> 4, ln = lane & 15;
  const size_t bm = (size_t)blockIdx.x * 128;
  const size_t bn = (size_t)blockIdx.y * 64;
  const int wm = (wave >> 1) * 64, wn = (wave & 1) * 32;
  f32x4 acc[4][2] = {};
  const int srow = wave * 16 + (lane >> 2);
  const int scol = (lane & 3) * 8;

  const size_t r0 = bm + srow, r1 = bm + 64 + srow;
  // per-row, per-head 1/(l0+l1)
  float invA[8], invB[8];
  {
    const size_t q0 = r0 & 4095, b0 = r0 >> 12;
    const size_t q1 = r1 & 4095, b1 = r1 >> 12;
#pragma unroll
    for (int hh = 0; hh < 8; ++hh) {
      invA[hh] = 1.0f / (Lpart[(b0 * 8 + hh) * 4096 + q0] +
                         Lpart[65536 + (b0 * 8 + hh) * 4096 + q0]);
      invB[hh] = 1.0f / (Lpart[(b1 * 8 + hh) * 4096 + q1] +
                         Lpart[65536 + (b1 * 8 + hh) * 4096 + q1]);
    }
  }
  const float* A0a = Opart + r0 * 512;
  const float* A0b = Opart + (size_t)NTOK * DMODEL + r0 * 512;
  const float* A1a = Opart + r1 * 512;
  const float* A1b = Opart + (size_t)NTOK * DMODEL + r1 * 512;
  const unsigned short* Bg = Bt + (bn + srow) * 512 + scol;
  unsigned short* Bd = Bs + wave * 512;

  for (int kt = 0; kt < 512; kt += 32) {
    __syncthreads();
    gll16(Bg + kt, Bd);
    const int c0 = kt + scol;          // 8 f32, all within head c0>>6
    const int hh = c0 >> 6;
    {
      f32x4 xa = *(const f32x4*)(A0a + c0),  xa2 = *(const f32x4*)(A0a + c0 + 4);
      f32x4 xb = *(const f32x4*)(A0b + c0),  xb2 = *(const f32x4*)(A0b + c0 + 4);
      float iv = invA[hh];
      union { u16x8 v; unsigned u[4]; } pu;
      pu.u[0] = pack_bf2((xa[0] + xb[0]) * iv, (xa[1] + xb[1]) * iv);
      pu.u[1] = pack_bf2((xa[2] + xb[2]) * iv, (xa[3] + xb[3]) * iv);
      pu.u[2] = pack_bf2((xa2[0] + xb2[0]) * iv, (xa2[1] + xb2[1]) * iv);
      pu.u[3] = pack_bf2((xa2[2] + xb2[2]) * iv, (xa2[3] + xb2[3]) * iv);
      *(u16x8*)(As + srow * 32 + scol) = pu.v;
    }
    {
      f32x4 xa = *(const f32x4*)(A1a + c0),  xa2 = *(const f32x4*)(A1a + c0 + 4);
      f32x4 xb = *(const f32x4*)(A1b + c0),  xb2 = *(const f32x4*)(A1b + c0 + 4);
      float iv = invB[hh];
      union { u16x8 v; unsigned u[4]; } pu;
      pu.u[0] = pack_bf2((xa[0] + xb[0]) * iv, (xa[1] + xb[1]) * iv);
      pu.u[1] = pack_bf2((xa[2] + xb[2]) * iv, (xa[3] + xb[3]) * iv);
      pu.u[2] = pack_bf2((xa2[0] + xb2[0]) * iv, (xa2[1] + xb2[1]) * iv);
      pu.u[3] = pack_bf2((xa2[2] + xb2[2]) * iv, (xa2[3] + xb2[3]) * iv);
      *(u16x8*)(As + (64 + srow) * 32 + scol) = pu.v;
    }
    __syncthreads();
    s16x8 af[4], bfr[2];
#pragma unroll
    for (int i = 0; i < 4; i++)
      af[i] = *(const s16x8*)(As + (wm + i * 16 + ln) * 32 + q4 * 8);
#pragma unroll
    for (int i = 0; i < 2; i++)
      bfr[i] = *(const s16x8*)(Bs + (wn + i * 16 + ln) * 32 + q4 * 8);
#pragma unroll
    for (int mi = 0; mi < 4; mi++)
#pragma unroll
      for (int ni = 0; ni < 2; ni++)
        acc[mi][ni] = __builtin_amdgcn_mfma_f32_16x16x32_bf16(
            af[mi], bfr[ni], acc[mi][ni], 0, 0, 0);
  }
#pragma unroll
  for (int mi = 0; mi < 4; mi++)
#pragma unroll
    for (int r = 0; r < 4; ++r) {
      size_t row = bm + wm + mi * 16 + q4 * 4 + r;
#pragma unroll
      for (int ni = 0; ni < 2; ni++)
        C[row * 512 + bn + wn + ni * 16 + ln] = acc[mi][ni][r];
    }
}

extern "C" void kernel_launch(void* const* d_in, const int* in_sizes, int n_in,
                              void* d_out, int out_size, void* d_ws, size_t ws_size,
                              hipStream_t stream) {
  const float* x  = (const float*)d_in[0];
  const float* Wq = (const float*)d_in[1];
  const float* Wk = (const float*)d_in[2];
  const float* Wv = (const float*)d_in[3];
  const float* Wo = (const float*)d_in[4];

  char* ws = (char*)d_ws;
  unsigned short* xb    = (unsigned short*)(ws);              //  8,388,608
  unsigned short* Wall  = (unsigned short*)(ws + 8388608);    //  2,097,152
  unsigned short* QKb   = (unsigned short*)(ws + 10485760);   // 16,777,216
  unsigned short* Vtb   = (unsigned short*)(ws + 27262976);   //  8,388,608
  float*          Opart = (float*)(ws + 35651584);            // 33,554,432
  float*          Lpart = (float*)(ws + 69206016);            //    524,288

  const float C2 = 0.125f * 1.44269504088896f;  // 1/sqrt(64) * log2(e)

  hipLaunchKernelGGL(prep_kernel, dim3(1280), dim3(256), 0, stream,
                     x, Wq, Wk, Wv, Wo, xb, Wall, C2);
  hipLaunchKernelGGL(gemm_qkv, dim3(64, 12), dim3(256), 0, stream,
                     xb, Wall, QKb, Vtb);
  hipLaunchKernelGGL(attn_kernel, dim3(32, 8, 4), dim3(256), 0, stream,
                     QKb, Vtb, Opart, Lpart);
  hipLaunchKernelGGL(gemm_out, dim3(64, 8), dim3(256), 0, stream,
                     Opart, Lpart, Wall + 3 * 262144, (float*)d_out);
}

// Round 12
// 190.717 us; speedup vs baseline: 1.0460x; 1.0460x over previous
//
#include <hip/hip_runtime.h>
#include <hip/hip_bf16.h>

// MultiHeadSelfAttention  B=2, S=4096, D=512, H=8, dk=64
// R12: composition of proven-best pieces:
//  - attn: R11 low-register body (M=32/wave, dbuf K/V, 1 barrier/tile,
//    S^T=K*Q^T in-register P packing, 80+32 regs) x key-split grid (32,8,4).
//  - combine: R10's separate streaming kernel (R11's combine-in-gemm_out
//    re-read Opart 8x -> +20us; reverted).
//  - gemm_out: R10's bf16-Oc version.
// kappa(m) = 32*(m>>5) + 8*((m>>2)&3) + 4*((m>>4)&1) + (m&3)  per 64-group,
// baked into V^T global layout so P packs in-register into PV A-frags.

#define DMODEL 512
#define SEQ    4096
#define NTOK   8192
#define LDQK   1024

using f32x4 = __attribute__((ext_vector_type(4))) float;
using s16x8 = __attribute__((ext_vector_type(8))) short;
using u16x8 = __attribute__((ext_vector_type(8))) unsigned short;

static __device__ __forceinline__ unsigned short f2bf(float f) {
  union { float f; unsigned u; } v; v.f = f;
  unsigned r = v.u + 0x7fff + ((v.u >> 16) & 1);   // RNE
  return (unsigned short)(r >> 16);
}

static __device__ __forceinline__ unsigned pack_bf2(float lo, float hi) {
  __hip_bfloat162 t = __float22bfloat162_rn(make_float2(lo, hi));
  union { __hip_bfloat162 b; unsigned u; } c; c.b = t; return c.u;
}

// async global->LDS, 16B per lane; lds base wave-uniform, lane i -> base+16i.
static __device__ __forceinline__ void gll16(const void* g, void* l) {
  __builtin_amdgcn_global_load_lds(
      (const __attribute__((address_space(1))) unsigned int*)g,
      (__attribute__((address_space(3))) unsigned int*)l, 16, 0, 0);
}

// Fused prep: blocks 0..1023 cast x -> bf16; blocks 1024..1279 transpose one
// 64x64 tile of one W into Wall = [Wq'|Wk|Wv|Wo] (N-major), Wq scaled by c2.
__global__ void prep_kernel(const float* __restrict__ x,
                            const float* __restrict__ Wq,
                            const float* __restrict__ Wk,
                            const float* __restrict__ Wv,
                            const float* __restrict__ Wo,
                            unsigned short* __restrict__ xb,
                            unsigned short* __restrict__ Wall, float c2) {
  __shared__ float T[64][65];
  const int bx = blockIdx.x;
  if (bx < 1024) {
    for (int i = bx * 256 + threadIdx.x; i < NTOK * DMODEL / 4; i += 262144) {
      float4 v = ((const float4*)x)[i];
      ushort4 o;
      o.x = f2bf(v.x); o.y = f2bf(v.y); o.z = f2bf(v.z); o.w = f2bf(v.w);
      ((ushort4*)xb)[i] = o;
    }
    return;
  }
  const int t = bx - 1024;
  const int y = t >> 6, sub = t & 63;
  const float* W = (y == 0) ? Wq : (y == 1) ? Wk : (y == 2) ? Wv : Wo;
  const float scale = (y == 0) ? c2 : 1.0f;
  const int tk = (sub & 7) * 64;
  const int tn = (sub >> 3) * 64;
  const int r  = threadIdx.x >> 2;
  const int cq = threadIdx.x & 3;
#pragma unroll
  for (int i = 0; i < 4; ++i) {
    int c = (cq + 4 * i) * 4;
    float4 v = *(const float4*)&W[(size_t)(tk + r) * 512 + tn + c];
    T[r][c + 0] = v.x * scale; T[r][c + 1] = v.y * scale;
    T[r][c + 2] = v.z * scale; T[r][c + 3] = v.w * scale;
  }
  __syncthreads();
  const int n  = threadIdx.x >> 2;
  const int k0 = (threadIdx.x & 3) * 16;
#pragma unroll
  for (int j4 = 0; j4 < 4; ++j4) {
    ushort4 o;
    o.x = f2bf(T[k0 + j4 * 4 + 0][n]);
    o.y = f2bf(T[k0 + j4 * 4 + 1][n]);
    o.z = f2bf(T[k0 + j4 * 4 + 2][n]);
    o.w = f2bf(T[k0 + j4 * 4 + 3][n]);
    *(ushort4*)&Wall[(size_t)y * 262144 + (size_t)(tn + n) * 512 + tk + k0 + j4 * 4] = o;
  }
}

// Fused QK + V^T GEMM. grid (64, 12). global_load_lds staging (m97 2-barrier).
//  by 0..7 : QK block  — C[8192 x 1024] = xb @ [Wq'|Wk]^T, bf16 row-major.
//  by 8..11: V^T block — C[512 x 8192] = Wv_t @ xb^T, stored batched
//            [b][m=h*64+dk][s] with kappa-permuted s within 64-groups.
__global__ __launch_bounds__(256, 3) void gemm_qkv(
    const unsigned short* __restrict__ xb,
    const unsigned short* __restrict__ Wall,
    unsigned short* __restrict__ QKb,
    unsigned short* __restrict__ Vtb)
{
  __shared__ unsigned short As[128 * 32];
  __shared__ unsigned short Bs[128 * 32];
  const int by = blockIdx.y;
  const bool vmode = (by >= 8);
  const unsigned short* A  = vmode ? (Wall + 2 * 262144) : xb;
  const unsigned short* Bt = vmode ? xb : Wall;
  const size_t bm = vmode ? (size_t)(by - 8) * 128 : (size_t)blockIdx.x * 128;
  const size_t bn = vmode ? (size_t)blockIdx.x * 128 : (size_t)by * 128;
  const int tid  = threadIdx.x;
  const int wave = tid >> 6, lane = tid & 63;
  const int q4 = lane >> 4, ln = lane & 15;
  const int wm = (wave >> 1) * 64, wn = (wave & 1) * 64;
  f32x4 acc[4][4] = {};
  const int srow = wave * 16 + (lane >> 2);
  const int scol = (lane & 3) * 8;

  const unsigned short* Ag  = A  + (bm + srow)      * 512 + scol;
  const unsigned short* Ag2 = A  + (bm + 64 + srow) * 512 + scol;
  const unsigned short* Bg  = Bt + (bn + srow)      * 512 + scol;
  const unsigned short* Bg2 = Bt + (bn + 64 + srow) * 512 + scol;
  unsigned short* Ad  = As + wave * 512;
  unsigned short* Ad2 = As + 2048 + wave * 512;
  unsigned short* Bd  = Bs + wave * 512;
  unsigned short* Bd2 = Bs + 2048 + wave * 512;

  for (int kt = 0; kt < 512; kt += 32) {
    __syncthreads();
    gll16(Ag + kt,  Ad);
    gll16(Ag2 + kt, Ad2);
    gll16(Bg + kt,  Bd);
    gll16(Bg2 + kt, Bd2);
    __syncthreads();
    s16x8 af[4], bfr[4];
#pragma unroll
    for (int i = 0; i < 4; i++)
      af[i] = *(const s16x8*)(As + (wm + i * 16 + ln) * 32 + q4 * 8);
#pragma unroll
    for (int i = 0; i < 4; i++)
      bfr[i] = *(const s16x8*)(Bs + (wn + i * 16 + ln) * 32 + q4 * 8);
#pragma unroll
    for (int mi = 0; mi < 4; mi++)
#pragma unroll
      for (int ni = 0; ni < 4; ni++)
        acc[mi][ni] = __builtin_amdgcn_mfma_f32_16x16x32_bf16(
            af[mi], bfr[ni], acc[mi][ni], 0, 0, 0);
  }
#pragma unroll
  for (int mi = 0; mi < 4; mi++)
#pragma unroll
    for (int r = 0; r < 4; ++r) {
      size_t row = bm + wm + mi * 16 + q4 * 4 + r;
#pragma unroll
      for (int ni = 0; ni < 4; ni++) {
        size_t col = bn + wn + ni * 16 + ln;
        unsigned short hv = f2bf(acc[mi][ni][r]);
        if (!vmode) {
          QKb[row * 1024 + col] = hv;
        } else {
          int b = (int)(col >> 12), s = (int)(col & 4095);
          // kappa(s%64): slot holding key s for PV A-frag alignment
          int sp = (s & ~63) | (s & 32) | (((s >> 2) & 3) << 3) |
                   (((s >> 4) & 1) << 2) | (s & 3);
          Vtb[(size_t)b * 2097152 + row * 4096 + sp] = hv;
        }
      }
    }
}

// Flash-lite attention, key-split, low-register body.
// grid (32 qt, 8 h, 4 z=b*2+ck) = 1024 blocks; 4 waves x 32 q-rows = 128
// q-rows/block; each block covers keys [ck*2048, ck*2048+2048) in 32 tiles.
// S^T = K*Q^T; P packed in-register into PV A-frags (kappa slots). Dbuf K/V,
// ONE barrier/tile. Writes f32 O/l chunk-partials (combine kernel normalizes).
// launch_bounds(256,2): do NOT raise (R9: (256,4) forced spills, ~2GB traffic).
__global__ __launch_bounds__(256, 2) void attn_kernel(
    const unsigned short* __restrict__ QK,   // NTOK x 1024 [Q'|K]
    const unsigned short* __restrict__ Vt,   // [b*8+h][64 dk][4096 s-kappa]
    float* __restrict__ Opart,               // [ck][8192][512] f32
    float* __restrict__ Lpart)               // [ck][b*8+h][4096] f32
{
  const int qt = blockIdx.x, h = blockIdx.y, z = blockIdx.z;
  const int b = z >> 1, ck = z & 1;
  const int tid = threadIdx.x, wave = tid >> 6, lane = tid & 63;
  const int q4 = lane >> 4, ln = lane & 15;
  __shared__ unsigned short Ks[2][64 * 72];   // [buf][key][dk]
  __shared__ unsigned short Vs[2][64 * 72];   // [buf][dk][key-kappa]
  const size_t rowbase = (size_t)b * SEQ;
  const size_t qrow0   = (size_t)qt * 128 + wave * 32;
  const unsigned short* Kp  = QK + rowbase * LDQK + 512 + h * 64;
  const unsigned short* VTp = Vt + ((size_t)(b * 8 + h) * 64) * SEQ;

  s16x8 qf[2][2];   // B-frags: B[n=ln (q)][k=q4*8+j]
#pragma unroll
  for (int mf = 0; mf < 2; ++mf) {
    const unsigned short* q = QK + (rowbase + qrow0 + mf * 16 + ln) * LDQK + h * 64;
    qf[mf][0] = *(const s16x8*)(q + q4 * 8);
    qf[mf][1] = *(const s16x8*)(q + 32 + q4 * 8);
  }
  f32x4 o[2][4] = {};
  float lp[2] = {};                     // per-lane l partials (q = ln)

  const int srow = tid >> 2;            // 0..63
  const int scol = (tid & 3) * 16;      // 0,16,32,48

  const unsigned short* kgp = Kp  + (size_t)(ck * 2048 + srow) * LDQK + scol;
  const unsigned short* vgp = VTp + (size_t)srow * SEQ + ck * 2048 + scol;

  // tile 0 -> regs -> buf0; prefetch tile 1 -> regs
  u16x8 kr  = *(const u16x8*)kgp;
  u16x8 kr2 = *(const u16x8*)(kgp + 8);
  u16x8 vr  = *(const u16x8*)vgp;
  u16x8 vr2 = *(const u16x8*)(vgp + 8);
  *(u16x8*)(Ks[0] + srow * 72 + scol)     = kr;
  *(u16x8*)(Ks[0] + srow * 72 + scol + 8) = kr2;
  *(u16x8*)(Vs[0] + srow * 72 + scol)     = vr;
  *(u16x8*)(Vs[0] + srow * 72 + scol + 8) = vr2;
  kgp += (size_t)64 * LDQK;  vgp += 64;
  kr  = *(const u16x8*)kgp;
  kr2 = *(const u16x8*)(kgp + 8);
  vr  = *(const u16x8*)vgp;
  vr2 = *(const u16x8*)(vgp + 8);
  __syncthreads();

  for (int t = 0; t < 32; ++t) {
    const int cur = t & 1;
    const unsigned short* Kc = Ks[cur];
    const unsigned short* Vc = Vs[cur];

    // S^T = K Q'^T : A=K frags (m=key), B=Q frags (n=q). K shared across mf.
    f32x4 s4[2][4] = {};
#pragma unroll
    for (int ni = 0; ni < 4; ni++) {
      const unsigned short* kb = Kc + (ni * 16 + ln) * 72 + q4 * 8;
      s16x8 kf0 = *(const s16x8*)kb;
      s16x8 kf1 = *(const s16x8*)(kb + 32);
#pragma unroll
      for (int mf = 0; mf < 2; ++mf) {
        s4[mf][ni] = __builtin_amdgcn_mfma_f32_16x16x32_bf16(kf0, qf[mf][0], s4[mf][ni], 0, 0, 0);
        s4[mf][ni] = __builtin_amdgcn_mfma_f32_16x16x32_bf16(kf1, qf[mf][1], s4[mf][ni], 0, 0, 0);
      }
    }
    // hoist V frags (independent of exp2 chain)
    s16x8 vf[2][4];
#pragma unroll
    for (int ks = 0; ks < 2; ++ks)
#pragma unroll
      for (int ni = 0; ni < 4; ni++)
        vf[ks][ni] = *(const s16x8*)(Vc + (ni * 16 + ln) * 72 + ks * 32 + q4 * 8);

    // p = exp2(s^T): all 16 values belong to q=ln. Pack straight into PV
    // A-frags: elem j of pf[ks] = e[ni=2ks+(j>>2)][r=j&3]  (kappa-aligned).
    s16x8 pf[2][2];
#pragma unroll
    for (int mf = 0; mf < 2; ++mf) {
      float e[4][4];
      float ls = 0.f;
#pragma unroll
      for (int ni = 0; ni < 4; ni++)
#pragma unroll
        for (int r = 0; r < 4; ++r) {
          e[ni][r] = __builtin_amdgcn_exp2f(s4[mf][ni][r]);
          ls += e[ni][r];
        }
      lp[mf] += ls;
#pragma unroll
      for (int ks = 0; ks < 2; ++ks) {
        union { s16x8 v; unsigned u[4]; } pu;
        pu.u[0] = pack_bf2(e[2 * ks][0],     e[2 * ks][1]);
        pu.u[1] = pack_bf2(e[2 * ks][2],     e[2 * ks][3]);
        pu.u[2] = pack_bf2(e[2 * ks + 1][0], e[2 * ks + 1][1]);
        pu.u[3] = pack_bf2(e[2 * ks + 1][2], e[2 * ks + 1][3]);
        pf[mf][ks] = pu.v;
      }
    }
    // O += P V
#pragma unroll
    for (int ks = 0; ks < 2; ++ks)
#pragma unroll
      for (int ni = 0; ni < 4; ni++)
#pragma unroll
        for (int mf = 0; mf < 2; ++mf)
          o[mf][ni] = __builtin_amdgcn_mfma_f32_16x16x32_bf16(pf[mf][ks], vf[ks][ni], o[mf][ni], 0, 0, 0);

    // stage tile t+1 into other buffer; prefetch tile t+2
    if (t + 1 < 32) {
      unsigned short* Kn = Ks[cur ^ 1];
      unsigned short* Vn = Vs[cur ^ 1];
      *(u16x8*)(Kn + srow * 72 + scol)     = kr;
      *(u16x8*)(Kn + srow * 72 + scol + 8) = kr2;
      *(u16x8*)(Vn + srow * 72 + scol)     = vr;
      *(u16x8*)(Vn + srow * 72 + scol + 8) = vr2;
      if (t + 2 < 32) {
        kgp += (size_t)64 * LDQK;  vgp += 64;
        kr  = *(const u16x8*)kgp;
        kr2 = *(const u16x8*)(kgp + 8);
        vr  = *(const u16x8*)vgp;
        vr2 = *(const u16x8*)(vgp + 8);
      }
    }
    __syncthreads();   // single barrier per tile
  }
  // l: sum the 4 q4-replicas; lane (q4==0, ln) holds l for q = ln
#pragma unroll
  for (int mf = 0; mf < 2; ++mf) {
    float l = lp[mf];
    l += __shfl_xor(l, 16, 64);
    l += __shfl_xor(l, 32, 64);
    if (q4 == 0)
      Lpart[(size_t)ck * 65536 + (size_t)(b * 8 + h) * 4096 + qrow0 + mf * 16 + ln] = l;
  }
  // O chunk-partials (f32, un-normalized)
  float* Opc = Opart + (size_t)ck * NTOK * DMODEL;
#pragma unroll
  for (int mf = 0; mf < 2; ++mf)
#pragma unroll
    for (int r = 0; r < 4; ++r) {
      size_t row = rowbase + qrow0 + mf * 16 + q4 * 4 + r;
#pragma unroll
      for (int ni = 0; ni < 4; ni++)
        Opc[row * DMODEL + h * 64 + ni * 16 + ln] = o[mf][ni][r];
    }
}

// combine: Oc[row][c] = (Op0+Op1)/(l0+l1), bf16. grid 4096 x 256.
__global__ void combine_kernel(const float* __restrict__ Opart,
                               const float* __restrict__ Lpart,
                               unsigned short* __restrict__ Oc) {
  int i = blockIdx.x * 256 + threadIdx.x;       // 0..1048575
  int row = i >> 7;                             // 0..8191
  int c4  = (i & 127) * 4;                      // 0..508
  int b = row >> 12, qrow = row & 4095, h = c4 >> 6;
  float l = Lpart[(size_t)(b * 8 + h) * 4096 + qrow] +
            Lpart[65536 + (size_t)(b * 8 + h) * 4096 + qrow];
  float inv = 1.0f / l;
  f32x4 a = *(const f32x4*)(Opart + (size_t)row * 512 + c4);
  f32x4 c = *(const f32x4*)(Opart + (size_t)NTOK * DMODEL + (size_t)row * 512 + c4);
  float r0 = (a[0] + c[0]) * inv, r1 = (a[1] + c[1]) * inv;
  float r2 = (a[2] + c[2]) * inv, r3 = (a[3] + c[3]) * inv;
  uint2 w;
  w.x = pack_bf2(r0, r1);
  w.y = pack_bf2(r2, r3);
  *(uint2*)&Oc[(size_t)row * 512 + c4] = w;
}

// out = Oc @ Wo^T : M=8192 N=512 K=512, tile 128x64 (512 blocks = 2/CU), f32.
__global__ __launch_bounds__(256, 3) void gemm_out(
    const unsigned short* __restrict__ A,
    const unsigned short* __restrict__ Bt,
    float* __restrict__ C)
{
  __shared__ unsigned short As[128 * 32];
  __shared__ unsigned short Bs[64 * 32];
  const int tid  = threadIdx.x;
  const int wave = tid >> 6, lane = tid & 63;
  const int q4 = lane >> 4, ln = lane & 15;
  const size_t bm = (size_t)blockIdx.x * 128;
  const size_t bn = (size_t)blockIdx.y * 64;
  const int wm = (wave >> 1) * 64, wn = (wave & 1) * 32;
  f32x4 acc[4][2] = {};
  const int srow = wave * 16 + (lane >> 2);
  const int scol = (lane & 3) * 8;

  const unsigned short* Ag  = A  + (bm + srow)      * 512 + scol;
  const unsigned short* Ag2 = A  + (bm + 64 + srow) * 512 + scol;
  const unsigned short* Bg  = Bt + (bn + srow)      * 512 + scol;
  unsigned short* Ad  = As + wave * 512;
  unsigned short* Ad2 = As + 2048 + wave * 512;
  unsigned short* Bd  = Bs + wave * 512;

  for (int kt = 0; kt < 512; kt += 32) {
    __syncthreads();
    gll16(Ag + kt,  Ad);
    gll16(Ag2 + kt, Ad2);
    gll16(Bg + kt,  Bd);
    __syncthreads();
    s16x8 af[4], bfr[2];
#pragma unroll
    for (int i = 0; i < 4; i++)
      af[i] = *(const s16x8*)(As + (wm + i * 16 + ln) * 32 + q4 * 8);
#pragma unroll
    for (int i = 0; i < 2; i++)
      bfr[i] = *(const s16x8*)(Bs + (wn + i * 16 + ln) * 32 + q4 * 8);
#pragma unroll
    for (int mi = 0; mi < 4; mi++)
#pragma unroll
      for (int ni = 0; ni < 2; ni++)
        acc[mi][ni] = __builtin_amdgcn_mfma_f32_16x16x32_bf16(
            af[mi], bfr[ni], acc[mi][ni], 0, 0, 0);
  }
#pragma unroll
  for (int mi = 0; mi < 4; mi++)
#pragma unroll
    for (int r = 0; r < 4; ++r) {
      size_t row = bm + wm + mi * 16 + q4 * 4 + r;
#pragma unroll
      for (int ni = 0; ni < 2; ni++)
        C[row * 512 + bn + wn + ni * 16 + ln] = acc[mi][ni][r];
    }
}

extern "C" void kernel_launch(void* const* d_in, const int* in_sizes, int n_in,
                              void* d_out, int out_size, void* d_ws, size_t ws_size,
                              hipStream_t stream) {
  const float* x  = (const float*)d_in[0];
  const float* Wq = (const float*)d_in[1];
  const float* Wk = (const float*)d_in[2];
  const float* Wv = (const float*)d_in[3];
  const float* Wo = (const float*)d_in[4];

  char* ws = (char*)d_ws;
  unsigned short* xb    = (unsigned short*)(ws);              //  8,388,608
  unsigned short* Wall  = (unsigned short*)(ws + 8388608);    //  2,097,152
  unsigned short* QKb   = (unsigned short*)(ws + 10485760);   // 16,777,216
  unsigned short* Vtb   = (unsigned short*)(ws + 27262976);   //  8,388,608
  unsigned short* Oc    = (unsigned short*)(ws + 35651584);   //  8,388,608
  float*          Opart = (float*)(ws + 44040192);            // 33,554,432
  float*          Lpart = (float*)(ws + 77594624);            //    524,288

  const float C2 = 0.125f * 1.44269504088896f;  // 1/sqrt(64) * log2(e)

  hipLaunchKernelGGL(prep_kernel, dim3(1280), dim3(256), 0, stream,
                     x, Wq, Wk, Wv, Wo, xb, Wall, C2);
  hipLaunchKernelGGL(gemm_qkv, dim3(64, 12), dim3(256), 0, stream,
                     xb, Wall, QKb, Vtb);
  hipLaunchKernelGGL(attn_kernel, dim3(32, 8, 4), dim3(256), 0, stream,
                     QKb, Vtb, Opart, Lpart);
  hipLaunchKernelGGL(combine_kernel, dim3(4096), dim3(256), 0, stream,
                     Opart, Lpart, Oc);
  hipLaunchKernelGGL(gemm_out, dim3(64, 8), dim3(256), 0, stream,
                     Oc, Wall + 3 * 262144, (float*)d_out);
}